// Round 2
// baseline (386.712 us; speedup 1.0000x reference)
//
#include <hip/hip_runtime.h>

#define BB 512
#define SS 1024
#define TT 64

__device__ __forceinline__ float wsum64(float v) {
#pragma unroll
  for (int off = 32; off > 0; off >>= 1) v += __shfl_xor(v, off, 64);
  return v;
}

// X-macro list: apply M(i) for i = 0..31 (one wave's half of the state dim)
#define H_LIST(M) \
  M(0) M(1) M(2) M(3) M(4) M(5) M(6) M(7) \
  M(8) M(9) M(10) M(11) M(12) M(13) M(14) M(15) \
  M(16) M(17) M(18) M(19) M(20) M(21) M(22) M(23) \
  M(24) M(25) M(26) M(27) M(28) M(29) M(30) M(31)

// Broadcast lane (W*32 + i) of the state vector held in pb_ (readlane -> SGPR).
#define RLW(i) __int_as_float(__builtin_amdgcn_readlane(pb_, (W) * 32 + (i)))

#define FMAH4(i0, i1, i2, i3)    \
  a0 = fmaf(RLW(i0), E##i0, a0); \
  a1 = fmaf(RLW(i1), E##i1, a1); \
  a2 = fmaf(RLW(i2), E##i2, a2); \
  a3 = fmaf(RLW(i3), E##i3, a3);

#define FMA_HALF        \
  FMAH4(0, 1, 2, 3)     \
  FMAH4(4, 5, 6, 7)     \
  FMAH4(8, 9, 10, 11)   \
  FMAH4(12, 13, 14, 15) \
  FMAH4(16, 17, 18, 19) \
  FMAH4(20, 21, 22, 23) \
  FMAH4(24, 25, 26, 27) \
  FMAH4(28, 29, 30, 31)

// One recurrence step, linear domain, delayed scalar normalization.
// Two waves (W=0,1) cooperate on one chain: wave W sums its 32-term half of
// s_j = sum_i p_i E_ij (fwd; bwd symmetric with rows/cols swapped), halves are
// combined via a double-buffered LDS slot with ONE barrier per step.
// fwd (DIR=0): broadcast p; p' = s * (f_j * inv)
// bwd (DIR=1): broadcast t_j = p_j * f_j * inv ; p' = s
// inv = 1/readfirstlane(s) from the PREVIOUS step (off critical path).
#define CRF_STEP2(ev, mkv, BUF)                                                     \
  do {                                                                              \
    float f_ = __expf((ev) * (mkv));                                                \
    float pv_ = (DIR == 1) ? p * (f_ * inv) : p;                                    \
    int pb_ = __float_as_int(pv_);                                                  \
    float a0 = 0.f, a1 = 0.f, a2 = 0.f, a3 = 0.f;                                   \
    FMA_HALF                                                                        \
    float h_ = (a0 + a1) + (a2 + a3);                                               \
    xch[BUF][W][lane] = h_;                                                         \
    __syncthreads();                                                                \
    float s_ = h_ + xch[BUF][1 - W][lane];                                          \
    p = (DIR == 0) ? s_ * (f_ * inv) : s_;                                          \
    float rn_ = __int_as_float(__builtin_amdgcn_readfirstlane(__float_as_int(s_))); \
    inv = __builtin_amdgcn_rcpf(rn_);                                               \
    float lg_ = __logf(rn_);                                                        \
    Lacc += lg_;                                                                    \
    lastlg = lg_;                                                                   \
  } while (0)

template <int DIR, int W>
__device__ __forceinline__ void part_run2(int b, int lane, const float* __restrict__ em,
                                          const float* __restrict__ mask,
                                          const float* __restrict__ trans,
                                          float* __restrict__ outv,
                                          float (*xch)[2][TT]) {
  // Per-lane E fragment: 32 NAMED scalars (half the matrix per wave).
  // fwd: wave W, lane j holds E[i][j] for i in [32W, 32W+32).
  // bwd: wave W, lane i holds E[i][j] for j in [32W, 32W+32).
  const float* tp = trans + (DIR == 0 ? lane : lane * TT);
#define EINIT(i) float E##i = __expf((DIR == 0) ? tp[((W)*32 + (i)) * TT] : tp[(W)*32 + (i)]);
  H_LIST(EINIT)
#undef EINIT

  const float* emb = em + (size_t)b * SS * TT;
  const float* mkb = mask + (size_t)b * SS;

  constexpr int NST = (DIR == 0) ? (SS / 2 - 1) : (SS / 2);  // 511 fwd, 512 bwd
  constexpr int S0 = (DIR == 0) ? 1 : (SS - 1);
  constexpr int SD = (DIR == 0) ? 1 : -1;
  constexpr int NG8 = NST / 8;    // full groups of 8 steps
  constexpr int TAIL8 = NST & 7;  // 7 fwd, 0 bwd

  float p = (DIR == 0) ? __expf(emb[lane] * mkb[0]) : 1.0f;
  float inv = 1.0f, Lacc = 0.0f, lastlg = 0.0f;

  // 8-deep emission prefetch (coalesced: lane j reads em[b][s][j])
  float ebuf[8];
#pragma unroll
  for (int k = 0; k < 8; ++k) ebuf[k] = emb[(S0 + SD * k) * TT + lane];
  const float* ep = emb + (ptrdiff_t)(S0 + SD * 8) * TT + lane;

  // mask: one coalesced vector load per 64 steps, broadcast via readlane
  float mv = 0.f;
  for (int t8 = 0; t8 < NG8; ++t8) {
    if ((t8 & 7) == 0) mv = mkb[S0 + SD * (t8 * 8 + lane)];
    const int base = (t8 & 7) * 8;
#pragma unroll
    for (int k = 0; k < 8; ++k) {
      float e = ebuf[k];
      ebuf[k] = *ep;  // prefetch step t+8; always in-bounds (fwd s<=519, bwd s>=504)
      ep += SD * TT;
      float mk = __int_as_float(
          __builtin_amdgcn_readlane(__float_as_int(mv), base + k));
      // global step index = t8*8+k; parity = k&1 (t8*8 is even) -> compile-time buf
      if (k & 1) {
        CRF_STEP2(e, mk, 1);
      } else {
        CRF_STEP2(e, mk, 0);
      }
    }
  }
  if constexpr (TAIL8 > 0) {  // fwd only; steps 504..510, parity = k&1
#pragma unroll
    for (int k = 0; k < TAIL8; ++k) {
      float e = ebuf[k];
      float mk = __int_as_float(
          __builtin_amdgcn_readlane(__float_as_int(mv), (NG8 & 7) * 8 + k));
      if (k & 1) {
        CRF_STEP2(e, mk, 1);
      } else {
        CRF_STEP2(e, mk, 0);
      }
    }
  }

  if (W == 0) outv[b * TT + lane] = __logf(p) + (Lacc - lastlg);
}

// Fused: blocks [0, 1024) = partition fwd/bwd (2 waves cooperate per chain);
//        blocks [1024, 3072) = gold score (128 threads, 2 s-values each)
__global__ void __launch_bounds__(128, 2)
    fused_kernel(const float* __restrict__ em, const int* __restrict__ tags,
                 const float* __restrict__ mask, const float* __restrict__ trans,
                 float* __restrict__ alpha, float* __restrict__ beta,
                 float* __restrict__ gpart) {
  __shared__ float xch[2][2][TT];
  __shared__ float gred[2];
  const int tid = threadIdx.x;
  const int bid = blockIdx.x;
  if (bid < 2 * BB) {
    const int b = bid >> 1;
    const int lane = tid & 63;
    const int w = tid >> 6;
    if ((bid & 1) == 0) {
      if (w == 0)
        part_run2<0, 0>(b, lane, em, mask, trans, alpha, xch);
      else
        part_run2<0, 1>(b, lane, em, mask, trans, alpha, xch);
    } else {
      if (w == 0)
        part_run2<1, 0>(b, lane, em, mask, trans, beta, xch);
      else
        part_run2<1, 1>(b, lane, em, mask, trans, beta, xch);
    }
  } else {
    const int gid = bid - 2 * BB;  // 0..2047
    const int b = gid >> 2, q = gid & 3;
    const int* tg = tags + b * SS;
    const float* mkb = mask + (size_t)b * SS;
    const float* emb = em + (size_t)b * SS * TT;
    float part = 0.f;
#pragma unroll
    for (int i = 0; i < 2; ++i) {
      int s = q * 256 + i * 128 + tid;
      int t1 = tg[s];
      float e = emb[s * TT + t1];
      float contrib = (s == 0) ? e : (trans[t1 * TT + tg[s - 1]] + e);
      part = fmaf(contrib, mkb[s], part);
    }
    part = wsum64(part);
    if ((tid & 63) == 0) gred[tid >> 6] = part;
    __syncthreads();
    if (tid == 0) gpart[gid] = gred[0] + gred[1];
  }
}

// Single block, 512 threads: thread b computes Z_b - gold_b, block-reduces, writes mean.
__global__ void combine_kernel(const float* __restrict__ alpha, const float* __restrict__ beta,
                               const float* __restrict__ gpart, float* __restrict__ out) {
  const int b = threadIdx.x;  // 0..511
  const float* av = alpha + b * TT;
  const float* bv = beta + b * TT;
  float m = -3.4e38f, s = 0.f;
#pragma unroll 8
  for (int j = 0; j < TT; ++j) {
    float v = av[j] + bv[j];
    float nm = fmaxf(m, v);
    s = s * __expf(m - nm) + __expf(v - nm);
    m = nm;
  }
  float Z = m + __logf(s);
  float g = gpart[4 * b] + gpart[4 * b + 1] + gpart[4 * b + 2] + gpart[4 * b + 3];
  float val = Z - g;
  val = wsum64(val);
  __shared__ float red[8];
  if ((threadIdx.x & 63) == 0) red[threadIdx.x >> 6] = val;
  __syncthreads();
  if (threadIdx.x == 0) {
    float t = 0.f;
#pragma unroll
    for (int w = 0; w < 8; ++w) t += red[w];
    out[0] = t * (1.0f / (float)BB);
  }
}

extern "C" void kernel_launch(void* const* d_in, const int* in_sizes, int n_in,
                              void* d_out, int out_size, void* d_ws, size_t ws_size,
                              hipStream_t stream) {
  const float* em = (const float*)d_in[0];
  const int* tags = (const int*)d_in[1];
  const float* mask = (const float*)d_in[2];
  const float* trans = (const float*)d_in[3];
  float* out = (float*)d_out;

  float* alpha = (float*)d_ws;      // 512*64
  float* beta = alpha + BB * TT;    // 512*64
  float* gpart = beta + BB * TT;    // 2048

  fused_kernel<<<2 * BB + 4 * BB, 128, 0, stream>>>(em, tags, mask, trans, alpha, beta, gpart);
  combine_kernel<<<1, BB, 0, stream>>>(alpha, beta, gpart, out);
}